// Round 9
// baseline (9010.679 us; speedup 1.0000x reference)
//
#include <hip/hip_runtime.h>

// LSTM persistent recurrence v9 for MI355X.
// v8 + primed poll: the 8 next-parity poll loads are issued at loop BOTTOM
// (right after publish), the bottom drain is deleted, and the loop-top
// vmcnt(0) overlaps poll RT with the tail (DMA/out). Stale fallback:
// single-line spin (a thread's 8 lines come from one producer-wave store)
// then one full reload. MFMA chains split into 2 accumulators each.

#define T_STEPS 2048
#define BATCH   64
#define DIM     256
#define HID     256
#define PKEEP   0.7f
#define NWG     64
#define RPG     16
#define REGION_U32 (RPG * HID * 2)       // 8192 u32 (8B pair per cell)
#define PLANE_U32  (4 * REGION_U32)      // 32768 u32 (128KB)
#define XEL     (T_STEPS * BATCH * DIM)

typedef __attribute__((ext_vector_type(8))) short s16x8;
typedef __attribute__((ext_vector_type(4))) float f32x4;
typedef __attribute__((ext_vector_type(4))) unsigned int u32x4;
typedef __attribute__((ext_vector_type(2))) unsigned int u32x2;
typedef unsigned int u32;
typedef unsigned short u16;

#define HBUF_OFF 4096
#define BIG_OFF  (1 << 20)
#define ZERO_INTS (2 * PLANE_U32)

#define HISEL 0x07060302u
#define LOSEL 0x05040100u

__device__ __forceinline__ u16 f2bf_rne(float f) {
  unsigned x = __float_as_uint(f);
  return (u16)((x + 0x7fffu + ((x >> 16) & 1u)) >> 16);
}
__device__ __forceinline__ float bf2f(u16 u) { return __uint_as_float(((unsigned)u) << 16); }
__device__ __forceinline__ float sigm(float v) { return 1.0f / (1.0f + __expf(-v)); }
__device__ __forceinline__ float tanh_f(float v) {
  float e = __expf(-2.0f * fabsf(v));
  float r = (1.0f - e) / (1.0f + e);
  return v < 0.0f ? -r : r;
}
__device__ __forceinline__ u32 packbf(float v) {
  u32 uh = __float_as_uint(v) & 0xFFFF0000u;
  u32 lo = (u32)f2bf_rne(v - __uint_as_float(uh));
  return uh | lo;
}
__device__ __forceinline__ void dev_st_u32x2(u32* p, u32x2 v) {
  asm volatile("global_store_dwordx2 %0, %1, off sc0 sc1" :: "v"(p), "v"(v) : "memory");
}
__device__ __forceinline__ void gload_lds16(const u32* g, u32* lds) {
  __builtin_amdgcn_global_load_lds(
      (const __attribute__((address_space(1))) u32*)g,
      (__attribute__((address_space(3))) u32*)lds, 16, 0, 0);
}
__device__ __forceinline__ void unpack8(u32x4 a, u32x4 b, s16x8& hi, s16x8& lo) {
  u32x4 H, L;
  H[0] = __builtin_amdgcn_perm(a[1], a[0], HISEL);
  H[1] = __builtin_amdgcn_perm(a[3], a[2], HISEL);
  H[2] = __builtin_amdgcn_perm(b[1], b[0], HISEL);
  H[3] = __builtin_amdgcn_perm(b[3], b[2], HISEL);
  L[0] = __builtin_amdgcn_perm(a[1], a[0], LOSEL);
  L[1] = __builtin_amdgcn_perm(a[3], a[2], LOSEL);
  L[2] = __builtin_amdgcn_perm(b[1], b[0], LOSEL);
  L[3] = __builtin_amdgcn_perm(b[3], b[2], LOSEL);
  hi = __builtin_bit_cast(s16x8, H);
  lo = __builtin_bit_cast(s16x8, L);
}

// 4x4 transpose between reg index (2 bits) and lane bits 2-3 (proven v8).
__device__ __forceinline__ void xpose4(f32x4& a, bool b2, bool b3) {
  {
    int t0 = __builtin_amdgcn_ds_swizzle(__float_as_int(a[1]), 0x101F);
    int u0 = __builtin_amdgcn_ds_swizzle(__float_as_int(a[0]), 0x101F);
    int t1 = __builtin_amdgcn_ds_swizzle(__float_as_int(a[3]), 0x101F);
    int u1 = __builtin_amdgcn_ds_swizzle(__float_as_int(a[2]), 0x101F);
    float A0 = b2 ? __int_as_float(t0) : a[0];
    float A1 = b2 ? a[1] : __int_as_float(u0);
    float A2 = b2 ? __int_as_float(t1) : a[2];
    float A3 = b2 ? a[3] : __int_as_float(u1);
    a[0] = A0; a[1] = A1; a[2] = A2; a[3] = A3;
  }
  {
    int t0 = __builtin_amdgcn_ds_swizzle(__float_as_int(a[2]), 0x201F);
    int u0 = __builtin_amdgcn_ds_swizzle(__float_as_int(a[0]), 0x201F);
    int t1 = __builtin_amdgcn_ds_swizzle(__float_as_int(a[3]), 0x201F);
    int u1 = __builtin_amdgcn_ds_swizzle(__float_as_int(a[1]), 0x201F);
    float A0 = b3 ? __int_as_float(t0) : a[0];
    float A2 = b3 ? a[2] : __int_as_float(u0);
    float A1 = b3 ? __int_as_float(t1) : a[1];
    float A3 = b3 ? a[3] : __int_as_float(u1);
    a[0] = A0; a[1] = A1; a[2] = A2; a[3] = A3;
  }
}

__global__ void lstm_zero_ws(u32* __restrict__ p) {
  int i = blockIdx.x * 256 + threadIdx.x;
  if (i < ZERO_INTS) p[i] = 0;
}

__global__ void lstm_xpack(const float* __restrict__ x, u32* __restrict__ xpk) {
  long i = ((long)blockIdx.x * 256 + threadIdx.x) * 4;
  if (i >= (long)XEL) return;
  f32x4 v = *(const f32x4*)(x + i);
  u32x4 o;
#pragma unroll
  for (int e = 0; e < 4; ++e) o[e] = packbf(v[e] * PKEEP);
  *(u32x4*)(xpk + i) = o;
}

// MODE: 0 = xpack planes, 1 = direct fp32
template <int MODE>
__device__ __forceinline__ void recur_body(
    const float* __restrict__ x, const int* __restrict__ lens,
    const float* __restrict__ W, const float* __restrict__ U,
    const float* __restrict__ bih, const float* __restrict__ bhh,
    float* __restrict__ out, u32* __restrict__ hbuf, const u32* __restrict__ xpk) {
  const int wg = blockIdx.x, tid = threadIdx.x;
  const int m = wg >> 4, n = wg & 15;
  const int lane = tid & 63, wave = tid >> 6;
  const int n16 = lane & 15, kgrp = lane >> 4;

  // ---- persistent B fragments, gate-interleaved (proven v8)
  const int ghc_w = n * 16 + wave * 4 + (n16 & 3);
  const int grow = (n16 >> 2) * HID + ghc_w;
  s16x8 BUh[8], BUl[8], BWh[8], BWl[8];
#pragma unroll
  for (int ks = 0; ks < 8; ++ks) {
    const int base = grow * DIM + ks * 32 + kgrp * 8;
#pragma unroll
    for (int e = 0; e < 8; ++e) {
      float uv = U[base + e];
      u16 uh = f2bf_rne(uv);
      BUh[ks][e] = (short)uh;
      BUl[ks][e] = (short)f2bf_rne(uv - bf2f(uh));
      float wv = W[base + e];
      u16 wh = f2bf_rne(wv);
      BWh[ks][e] = (short)wh;
      BWl[ks][e] = (short)f2bf_rne(wv - bf2f(wh));
    }
  }

  const bool b2 = (lane >> 2) & 1, b3 = (lane >> 3) & 1;
  const int row_l = kgrp * 4 + (n16 >> 2);
  const int gb = m * RPG + row_l;
  const float bi  = bih[0 * HID + ghc_w] + bhh[0 * HID + ghc_w];
  const float bfo = bih[1 * HID + ghc_w] + bhh[1 * HID + ghc_w];
  const float bg  = bih[2 * HID + ghc_w] + bhh[2 * HID + ghc_w];
  const float bo  = bih[3 * HID + ghc_w] + bhh[3 * HID + ghc_w];
  const int len = lens[gb];
  float hreg = 0.0f, creg = 0.0f;

  const int rh = tid >> 7, p = tid & 127;

  __shared__ u32 hstage[2][RPG * HID];
  __shared__ u32 xstage[2][RPG * HID];

  // ---- prologue: DMA x(0); prime poll loads for t=0 (parity 0)
  {
    const int R = wave * 4;
    const long tb = (long)(m * RPG) * DIM;
#pragma unroll
    for (int r = 0; r < 4; ++r) {
      const long src = tb + (long)(R + r) * DIM + 4 * (lane ^ ((R + r) & 15));
      if constexpr (MODE == 0) gload_lds16(xpk + src, &xstage[0][(R + r) * HID]);
      else                     gload_lds16((const u32*)x + src, &xstage[0][(R + r) * HID]);
    }
  }
  u32x4 P[8];
  {
    const u32* rb = hbuf + m * REGION_U32 + rh * (8 * 512) + p * 4;
#pragma unroll
    for (int j = 0; j < 8; ++j)
      asm volatile("global_load_dwordx4 %0, %1, off sc0 sc1"
                   : "=v"(P[j]) : "v"(rb + j * 512) : "memory");
  }

  for (int t = 0; t < T_STEPS; ++t) {
    const int par = t & 1;
    const u32* rb = hbuf + par * PLANE_U32 + m * REGION_U32 + rh * (8 * 512) + p * 4;

    // ---- arrival of primed loads (+ all tail VMEM from step t-1)
    asm volatile("s_waitcnt vmcnt(0)" ::: "memory");
    __builtin_amdgcn_sched_barrier(0);
    {
      bool stale = false;
#pragma unroll
      for (int j = 0; j < 8; ++j)
        stale |= (P[j][1] != (u32)t) || (P[j][3] != (u32)t);
      if (__any(stale)) {
        // single-line spin (thread's 8 lines come from ONE producer wave)
        u32x4 P0;
        do {
          asm volatile("global_load_dwordx4 %0, %1, off sc0 sc1"
                       : "=v"(P0) : "v"(rb) : "memory");
          asm volatile("s_waitcnt vmcnt(0)" ::: "memory");
          __builtin_amdgcn_sched_barrier(0);
        } while (__any((P0[1] != (u32)t) || (P0[3] != (u32)t)));
        // full reload + verify (rarely repeats)
        for (;;) {
          bool st2 = false;
#pragma unroll
          for (int j = 0; j < 8; ++j)
            asm volatile("global_load_dwordx4 %0, %1, off sc0 sc1"
                         : "=v"(P[j]) : "v"(rb + j * 512) : "memory");
          asm volatile("s_waitcnt vmcnt(0)" ::: "memory");
          __builtin_amdgcn_sched_barrier(0);
#pragma unroll
          for (int j = 0; j < 8; ++j)
            st2 |= (P[j][1] != (u32)t) || (P[j][3] != (u32)t);
          if (!__any(st2)) break;
        }
      }
    }

    // ---- stage h into hstage[par]: conflict-free ds_write_b64
#pragma unroll
    for (int j = 0; j < 8; ++j) {
      const int row = rh * 8 + j;
      const int byte = (row * 1024 + p * 8) ^ (row << 4);
      u32x2 v = {P[j][0], P[j][2]};
      *(u32x2*)((char*)hstage[par] + byte) = v;
    }
    __syncthreads();  // the only barrier per step

    // ---- gate GEMM: 4 independent accumulator chains
    const int swz = n16 << 4;
    f32x4 ah0 = {0.f, 0.f, 0.f, 0.f}, ah1 = {0.f, 0.f, 0.f, 0.f};
    f32x4 ax0 = {0.f, 0.f, 0.f, 0.f}, ax1 = {0.f, 0.f, 0.f, 0.f};
#pragma unroll
    for (int ks = 0; ks < 8; ++ks) {
      const int bb = n16 * 1024 + (kgrp * 8 + ks * 32) * 4;
      u32x4 h0 = *(const u32x4*)((const char*)hstage[par] + (bb ^ swz));
      u32x4 h1 = *(const u32x4*)((const char*)hstage[par] + ((bb + 16) ^ swz));
      s16x8 Hh, Hl, Xh, Xl;
      unpack8(h0, h1, Hh, Hl);
      if constexpr (MODE == 0) {
        u32x4 x0 = *(const u32x4*)((const char*)xstage[par] + (bb ^ swz));
        u32x4 x1 = *(const u32x4*)((const char*)xstage[par] + ((bb + 16) ^ swz));
        unpack8(x0, x1, Xh, Xl);
      } else {
        f32x4 f0 = *(const f32x4*)((const char*)xstage[par] + (bb ^ swz));
        f32x4 f1 = *(const f32x4*)((const char*)xstage[par] + ((bb + 16) ^ swz));
#pragma unroll
        for (int e = 0; e < 8; ++e) {
          float v = (e < 4 ? f0[e] : f1[e - 4]) * PKEEP;
          unsigned hb = __float_as_uint(v) & 0xFFFF0000u;
          Xh[e] = (short)(hb >> 16);
          Xl[e] = (short)(u16)(__float_as_uint(v - __uint_as_float(hb)) >> 16);
        }
      }
      if (ks & 1) {
        ah1 = __builtin_amdgcn_mfma_f32_16x16x32_bf16(Hh, BUh[ks], ah1, 0, 0, 0);
        ax1 = __builtin_amdgcn_mfma_f32_16x16x32_bf16(Xh, BWh[ks], ax1, 0, 0, 0);
        ah1 = __builtin_amdgcn_mfma_f32_16x16x32_bf16(Hl, BUh[ks], ah1, 0, 0, 0);
        ax1 = __builtin_amdgcn_mfma_f32_16x16x32_bf16(Xl, BWh[ks], ax1, 0, 0, 0);
        ah1 = __builtin_amdgcn_mfma_f32_16x16x32_bf16(Hh, BUl[ks], ah1, 0, 0, 0);
        ax1 = __builtin_amdgcn_mfma_f32_16x16x32_bf16(Xh, BWl[ks], ax1, 0, 0, 0);
      } else {
        ah0 = __builtin_amdgcn_mfma_f32_16x16x32_bf16(Hh, BUh[ks], ah0, 0, 0, 0);
        ax0 = __builtin_amdgcn_mfma_f32_16x16x32_bf16(Xh, BWh[ks], ax0, 0, 0, 0);
        ah0 = __builtin_amdgcn_mfma_f32_16x16x32_bf16(Hl, BUh[ks], ah0, 0, 0, 0);
        ax0 = __builtin_amdgcn_mfma_f32_16x16x32_bf16(Xl, BWh[ks], ax0, 0, 0, 0);
        ah0 = __builtin_amdgcn_mfma_f32_16x16x32_bf16(Hh, BUl[ks], ah0, 0, 0, 0);
        ax0 = __builtin_amdgcn_mfma_f32_16x16x32_bf16(Xh, BWl[ks], ax0, 0, 0, 0);
      }
    }

    // ---- in-wave gather: lane now holds its cell's i,f,g,o
    f32x4 g4 = (ah0 + ah1) + (ax0 + ax1);
    xpose4(g4, b2, b3);

    // ---- cell update + immediate publish
    float gi = g4[0] + bi, gf = g4[1] + bfo, gg = g4[2] + bg, go = g4[3] + bo;
    float it = sigm(gi), ft = sigm(gf), ot = sigm(go);
    float gt = tanh_f(gg);
    float cnew = ft * creg + it * gt;
    float hnew = ot * tanh_f(cnew);
    const bool act = (t < len);
    if (act) { creg = cnew; hreg = hnew; }
    {
      u32x2 pv = {packbf(hreg * PKEEP), (u32)(t + 1)};
      dev_st_u32x2(hbuf + (par ^ 1) * PLANE_U32 + m * REGION_U32 + row_l * 512 + ghc_w * 2, pv);
    }

    // ---- prime next poll (overlaps with producers finishing)
    {
      const u32* rbn = hbuf + (par ^ 1) * PLANE_U32 + m * REGION_U32 + rh * (8 * 512) + p * 4;
#pragma unroll
      for (int j = 0; j < 8; ++j)
        asm volatile("global_load_dwordx4 %0, %1, off sc0 sc1"
                     : "=v"(P[j]) : "v"(rbn + j * 512) : "memory");
    }

    // ---- x DMA for t+1 + out store (drained by next loop-top vmcnt)
    if (t + 1 < T_STEPS) {
      const int R = wave * 4;
      const long tb = (long)(t + 1) * (BATCH * DIM) + (long)(m * RPG) * DIM;
#pragma unroll
      for (int r = 0; r < 4; ++r) {
        const long src = tb + (long)(R + r) * DIM + 4 * (lane ^ ((R + r) & 15));
        if constexpr (MODE == 0) gload_lds16(xpk + src, &xstage[par ^ 1][(R + r) * HID]);
        else                     gload_lds16((const u32*)x + src, &xstage[par ^ 1][(R + r) * HID]);
      }
    }
    out[(long)t * (BATCH * HID) + gb * HID + ghc_w] = act ? hnew : 0.0f;
  }

  // ---- epilogue
  out[(long)T_STEPS * (BATCH * HID) + gb * HID + ghc_w] = hreg;
  out[(long)T_STEPS * (BATCH * HID) + BATCH * HID + gb * HID + ghc_w] = creg;
}

#define RECUR_PARAMS                                                          \
  const float* __restrict__ x, const int* __restrict__ lens,                  \
  const float* __restrict__ W, const float* __restrict__ U,                   \
  const float* __restrict__ bih, const float* __restrict__ bhh,               \
  float* __restrict__ out, u32* __restrict__ hbuf, const u32* __restrict__ xpk
#define RECUR_ARGS x, lens, W, U, bih, bhh, out, hbuf, xpk

__global__ __launch_bounds__(256, 1) void lstm_recur_v9_xpk(RECUR_PARAMS) { recur_body<0>(RECUR_ARGS); }
__global__ __launch_bounds__(256, 1) void lstm_recur_v9_dir(RECUR_PARAMS) { recur_body<1>(RECUR_ARGS); }

extern "C" void kernel_launch(void* const* d_in, const int* in_sizes, int n_in,
                              void* d_out, int out_size, void* d_ws, size_t ws_size,
                              hipStream_t stream) {
  const float* x   = (const float*)d_in[0];
  const int*   len = (const int*)d_in[1];
  const float* W   = (const float*)d_in[2];
  const float* U   = (const float*)d_in[3];
  const float* bih = (const float*)d_in[4];
  const float* bhh = (const float*)d_in[5];
  float* out = (float*)d_out;
  char*  ws  = (char*)d_ws;
  u32* hbuf = (u32*)(ws + HBUF_OFF);
  char* big = ws + BIG_OFF;

  lstm_zero_ws<<<dim3((ZERO_INTS + 255) / 256), dim3(256), 0, stream>>>(hbuf);

  const size_t need_xp = (size_t)BIG_OFF + (size_t)XEL * 4;  // ~129MB
  if (ws_size >= need_xp) {
    u32* xpk = (u32*)big;
    lstm_xpack<<<dim3(32768), dim3(256), 0, stream>>>(x, xpk);
    lstm_recur_v9_xpk<<<dim3(NWG), dim3(256), 0, stream>>>(x, len, W, U, bih, bhh, out, hbuf, xpk);
  } else {
    lstm_recur_v9_dir<<<dim3(NWG), dim3(256), 0, stream>>>(x, len, W, U, bih, bhh, out, hbuf, nullptr);
  }
}

// Round 14
// 4975.377 us; speedup vs baseline: 1.8111x; 1.8111x over previous
//
#include <hip/hip_runtime.h>

// LSTM v14 for MI355X.
// v12 structure, fp16 ELIMINATED (prime suspect for v10-v13's identical
// failures): Gx table stores pure x-preacts as bf16 pairs
// {bf16(i)<<16|bf16(f), bf16(g)<<16|bf16(o)}, encoded with f2bf_rne and
// decoded with &0xFFFF0000 / <<16 + uint_as_float — all session-proven ops.
// Bias stays in the consumer (fp32, v8-style). Producer = v8 x-chain
// verbatim. Consumer = v8 skeleton, h-only MFMAs. Fallback: v8 (5.19ms).

#define T_STEPS 2048
#define BATCH   64
#define DIM     256
#define HID     256
#define PKEEP   0.7f
#define RPG     16
#define TCHUNK  32
#define REGION_U32 (RPG * HID * 2)       // 8192 u32
#define PLANE_U32  (4 * REGION_U32)      // 32768 u32 (128KB)
#define XEL     (T_STEPS * BATCH * DIM)

typedef __attribute__((ext_vector_type(8))) short s16x8;
typedef __attribute__((ext_vector_type(4))) float f32x4;
typedef __attribute__((ext_vector_type(4))) unsigned int u32x4;
typedef __attribute__((ext_vector_type(2))) unsigned int u32x2;
typedef unsigned int u32;
typedef unsigned short u16;

#define HBUF_OFF 4096
#define BIG_OFF  (1 << 20)
#define ZERO_INTS (2 * PLANE_U32)

#define HISEL 0x07060302u
#define LOSEL 0x05040100u

__device__ __forceinline__ u16 f2bf_rne(float f) {
  unsigned x = __float_as_uint(f);
  return (u16)((x + 0x7fffu + ((x >> 16) & 1u)) >> 16);
}
__device__ __forceinline__ float bf2f(u16 u) { return __uint_as_float(((unsigned)u) << 16); }
__device__ __forceinline__ float sigm(float v) { return 1.0f / (1.0f + __expf(-v)); }
__device__ __forceinline__ float tanh_f(float v) {
  float e = __expf(-2.0f * fabsf(v));
  float r = (1.0f - e) / (1.0f + e);
  return v < 0.0f ? -r : r;
}
__device__ __forceinline__ u32 packbf(float v) {
  u32 uh = __float_as_uint(v) & 0xFFFF0000u;
  u32 lo = (u32)f2bf_rne(v - __uint_as_float(uh));
  return uh | lo;
}
__device__ __forceinline__ void dev_st_u32x2(u32* p, u32x2 v) {
  asm volatile("global_store_dwordx2 %0, %1, off sc0 sc1" :: "v"(p), "v"(v) : "memory");
}
__device__ __forceinline__ void gload_lds16(const u32* g, u32* lds) {
  __builtin_amdgcn_global_load_lds(
      (const __attribute__((address_space(1))) u32*)g,
      (__attribute__((address_space(3))) u32*)lds, 16, 0, 0);
}
__device__ __forceinline__ void unpack8(u32x4 a, u32x4 b, s16x8& hi, s16x8& lo) {
  u32x4 H, L;
  H[0] = __builtin_amdgcn_perm(a[1], a[0], HISEL);
  H[1] = __builtin_amdgcn_perm(a[3], a[2], HISEL);
  H[2] = __builtin_amdgcn_perm(b[1], b[0], HISEL);
  H[3] = __builtin_amdgcn_perm(b[3], b[2], HISEL);
  L[0] = __builtin_amdgcn_perm(a[1], a[0], LOSEL);
  L[1] = __builtin_amdgcn_perm(a[3], a[2], LOSEL);
  L[2] = __builtin_amdgcn_perm(b[1], b[0], LOSEL);
  L[3] = __builtin_amdgcn_perm(b[3], b[2], LOSEL);
  hi = __builtin_bit_cast(s16x8, H);
  lo = __builtin_bit_cast(s16x8, L);
}
// 4x4 reg<->lane-bit transpose (proven v8)
__device__ __forceinline__ void xpose4(f32x4& a, bool b2, bool b3) {
  {
    int t0 = __builtin_amdgcn_ds_swizzle(__float_as_int(a[1]), 0x101F);
    int u0 = __builtin_amdgcn_ds_swizzle(__float_as_int(a[0]), 0x101F);
    int t1 = __builtin_amdgcn_ds_swizzle(__float_as_int(a[3]), 0x101F);
    int u1 = __builtin_amdgcn_ds_swizzle(__float_as_int(a[2]), 0x101F);
    float A0 = b2 ? __int_as_float(t0) : a[0];
    float A1 = b2 ? a[1] : __int_as_float(u0);
    float A2 = b2 ? __int_as_float(t1) : a[2];
    float A3 = b2 ? a[3] : __int_as_float(u1);
    a[0] = A0; a[1] = A1; a[2] = A2; a[3] = A3;
  }
  {
    int t0 = __builtin_amdgcn_ds_swizzle(__float_as_int(a[2]), 0x201F);
    int u0 = __builtin_amdgcn_ds_swizzle(__float_as_int(a[0]), 0x201F);
    int t1 = __builtin_amdgcn_ds_swizzle(__float_as_int(a[3]), 0x201F);
    int u1 = __builtin_amdgcn_ds_swizzle(__float_as_int(a[1]), 0x201F);
    float A0 = b3 ? __int_as_float(t0) : a[0];
    float A2 = b3 ? a[2] : __int_as_float(u0);
    float A1 = b3 ? __int_as_float(t1) : a[1];
    float A3 = b3 ? a[3] : __int_as_float(u1);
    a[0] = A0; a[1] = A1; a[2] = A2; a[3] = A3;
  }
}

__global__ void lstm_zero_ws(u32* __restrict__ p) {
  int i = blockIdx.x * 256 + threadIdx.x;
  if (i < ZERO_INTS) p[i] = 0;
}

__global__ void lstm_xpack(const float* __restrict__ x, u32* __restrict__ xpk) {
  long i = ((long)blockIdx.x * 256 + threadIdx.x) * 4;
  if (i >= (long)XEL) return;
  f32x4 v = *(const f32x4*)(x + i);
  u32x4 o;
#pragma unroll
  for (int e = 0; e < 4; ++e) o[e] = packbf(v[e] * PKEEP);
  *(u32x4*)(xpk + i) = o;
}

// ---------- Gx producer: v8 x-chain verbatim; bf16-pair encode, no bias ------
__global__ __launch_bounds__(256, 1) void lstm_gxp14(
    const float* __restrict__ x, const float* __restrict__ W,
    u32* __restrict__ Gxb) {
  const int tid = threadIdx.x;
  const int n = blockIdx.x & 15, m = (blockIdx.x >> 4) & 3;
  const int tc = blockIdx.x >> 6;
  const int t0 = tc * TCHUNK;
  const int lane = tid & 63, wave = tid >> 6;
  const int n16 = lane & 15, kgrp = lane >> 4;

  const int ghc_w = n * 16 + wave * 4 + (n16 & 3);
  const int grow = (n16 >> 2) * HID + ghc_w;
  s16x8 BWh[8], BWl[8];
#pragma unroll
  for (int ks = 0; ks < 8; ++ks) {
    const int base = grow * DIM + ks * 32 + kgrp * 8;
#pragma unroll
    for (int e = 0; e < 8; ++e) {
      float wv = W[base + e];
      u16 wh = f2bf_rne(wv);
      BWh[ks][e] = (short)wh;
      BWl[ks][e] = (short)f2bf_rne(wv - bf2f(wh));
    }
  }

  const bool b2 = (lane >> 2) & 1, b3 = (lane >> 3) & 1;
  const int row_l = kgrp * 4 + (n16 >> 2);
  const int gb = m * RPG + row_l;

  __shared__ u32 xstage[2][RPG * HID];

  {
    const int R = wave * 4;
    const long tb = (long)t0 * (BATCH * DIM) + (long)(m * RPG) * DIM;
#pragma unroll
    for (int r = 0; r < 4; ++r) {
      const long src = tb + (long)(R + r) * DIM + 4 * (lane ^ ((R + r) & 15));
      gload_lds16((const u32*)x + src, &xstage[0][(R + r) * HID]);
    }
  }

  for (int ti = 0; ti < TCHUNK; ++ti) {
    const int t = t0 + ti, par = ti & 1;
    asm volatile("s_waitcnt vmcnt(0)" ::: "memory");
    __builtin_amdgcn_sched_barrier(0);
    __syncthreads();

    const int swz = n16 << 4;
    f32x4 ax = {0.f, 0.f, 0.f, 0.f};
#pragma unroll
    for (int ks = 0; ks < 8; ++ks) {
      const int bb = n16 * 1024 + (kgrp * 8 + ks * 32) * 4;
      f32x4 f0 = *(const f32x4*)((const char*)xstage[par] + (bb ^ swz));
      f32x4 f1 = *(const f32x4*)((const char*)xstage[par] + ((bb + 16) ^ swz));
      s16x8 Xh, Xl;
#pragma unroll
      for (int e = 0; e < 8; ++e) {
        float v = (e < 4 ? f0[e] : f1[e - 4]) * PKEEP;
        unsigned hb = __float_as_uint(v) & 0xFFFF0000u;
        Xh[e] = (short)(hb >> 16);
        Xl[e] = (short)(u16)(__float_as_uint(v - __uint_as_float(hb)) >> 16);
      }
      ax = __builtin_amdgcn_mfma_f32_16x16x32_bf16(Xh, BWh[ks], ax, 0, 0, 0);
      ax = __builtin_amdgcn_mfma_f32_16x16x32_bf16(Xl, BWh[ks], ax, 0, 0, 0);
      ax = __builtin_amdgcn_mfma_f32_16x16x32_bf16(Xh, BWl[ks], ax, 0, 0, 0);
    }

    f32x4 g4 = ax;
    xpose4(g4, b2, b3);

    // bf16-pair encode (proven bit ops; no bias — consumer adds fp32 bias)
    u32x2 pv;
    pv[0] = ((u32)f2bf_rne(g4[0]) << 16) | (u32)f2bf_rne(g4[1]);  // i | f
    pv[1] = ((u32)f2bf_rne(g4[2]) << 16) | (u32)f2bf_rne(g4[3]);  // g | o
    *(u32x2*)(Gxb + ((long)(t * BATCH + gb)) * 512 + ghc_w * 2) = pv;

    if (ti + 1 < TCHUNK) {
      const int R = wave * 4;
      const long tb = (long)(t + 1) * (BATCH * DIM) + (long)(m * RPG) * DIM;
#pragma unroll
      for (int r = 0; r < 4; ++r) {
        const long src = tb + (long)(R + r) * DIM + 4 * (lane ^ ((R + r) & 15));
        gload_lds16((const u32*)x + src, &xstage[par ^ 1][(R + r) * HID]);
      }
    }
  }
}

// ---------- consumer: v8 skeleton, h-only MFMAs, bf16-pair Gx decode ---------
__global__ __launch_bounds__(256, 1) void lstm_recur_v14(
    const float* __restrict__ x, const int* __restrict__ lens,
    const float* __restrict__ W, const float* __restrict__ U,
    const float* __restrict__ bih, const float* __restrict__ bhh,
    float* __restrict__ out, u32* __restrict__ hbuf, const u32* __restrict__ Gxb) {
  const int wg = blockIdx.x, tid = threadIdx.x;
  const int m = wg >> 4, n = wg & 15;
  const int lane = tid & 63, wave = tid >> 6;
  const int n16 = lane & 15, kgrp = lane >> 4;

  const int ghc_w = n * 16 + wave * 4 + (n16 & 3);
  const int grow = (n16 >> 2) * HID + ghc_w;
  s16x8 BUh[8], BUl[8];
#pragma unroll
  for (int ks = 0; ks < 8; ++ks) {
    const int base = grow * DIM + ks * 32 + kgrp * 8;
#pragma unroll
    for (int e = 0; e < 8; ++e) {
      float uv = U[base + e];
      u16 uh = f2bf_rne(uv);
      BUh[ks][e] = (short)uh;
      BUl[ks][e] = (short)f2bf_rne(uv - bf2f(uh));
    }
  }

  const bool b2 = (lane >> 2) & 1, b3 = (lane >> 3) & 1;
  const int row_l = kgrp * 4 + (n16 >> 2);
  const int gb = m * RPG + row_l;
  const float bi  = bih[0 * HID + ghc_w] + bhh[0 * HID + ghc_w];
  const float bfo = bih[1 * HID + ghc_w] + bhh[1 * HID + ghc_w];
  const float bg  = bih[2 * HID + ghc_w] + bhh[2 * HID + ghc_w];
  const float bo  = bih[3 * HID + ghc_w] + bhh[3 * HID + ghc_w];
  const int len = lens[gb];
  float hreg = 0.0f, creg = 0.0f;

  const int rh = tid >> 7, p = tid & 127;
  __shared__ u32 hstage[2][RPG * HID];

  // Gx prefetch for t=0
  u32x2 gxu = *(const u32x2*)(Gxb + ((long)gb) * 512 + ghc_w * 2);

  for (int t = 0; t < T_STEPS; ++t) {
    const int par = t & 1;

    // ---- poll h pair-lines (v8 verbatim)
    u32x4 P[8];
    {
      const u32* rb = hbuf + par * PLANE_U32 + m * REGION_U32 + rh * (8 * 512) + p * 4;
      for (;;) {
#pragma unroll
        for (int j = 0; j < 8; ++j)
          asm volatile("global_load_dwordx4 %0, %1, off sc0 sc1"
                       : "=v"(P[j]) : "v"(rb + j * 512) : "memory");
        asm volatile("s_waitcnt vmcnt(0)" ::: "memory");
        if (t == 0) break;
        bool stale = false;
#pragma unroll
        for (int j = 0; j < 8; ++j)
          stale |= (P[j][1] != (u32)t) || (P[j][3] != (u32)t);
        if (!__any(stale)) break;
      }
    }
    __builtin_amdgcn_sched_barrier(0);

    // ---- stage h (v8 verbatim)
#pragma unroll
    for (int j = 0; j < 8; ++j) {
      const int row = rh * 8 + j;
      const int byte = (row * 1024 + p * 8) ^ (row << 4);
      u32x2 v = {P[j][0], P[j][2]};
      *(u32x2*)((char*)hstage[par] + byte) = v;
    }
    __syncthreads();

    // ---- h-only gate GEMM: 24 MFMAs
    const int swz = n16 << 4;
    f32x4 ah = {0.f, 0.f, 0.f, 0.f};
#pragma unroll
    for (int ks = 0; ks < 8; ++ks) {
      const int bb = n16 * 1024 + (kgrp * 8 + ks * 32) * 4;
      u32x4 h0 = *(const u32x4*)((const char*)hstage[par] + (bb ^ swz));
      u32x4 h1 = *(const u32x4*)((const char*)hstage[par] + ((bb + 16) ^ swz));
      s16x8 Hh, Hl;
      unpack8(h0, h1, Hh, Hl);
      ah = __builtin_amdgcn_mfma_f32_16x16x32_bf16(Hh, BUh[ks], ah, 0, 0, 0);
      ah = __builtin_amdgcn_mfma_f32_16x16x32_bf16(Hl, BUh[ks], ah, 0, 0, 0);
      ah = __builtin_amdgcn_mfma_f32_16x16x32_bf16(Hh, BUl[ks], ah, 0, 0, 0);
    }

    // ---- gather + cell: bf16-pair decode (pure bit ops) + fp32 bias
    f32x4 g4 = ah;
    xpose4(g4, b2, b3);
    float gi = g4[0] + __uint_as_float(gxu[0] & 0xFFFF0000u) + bi;
    float gf = g4[1] + __uint_as_float(gxu[0] << 16)          + bfo;
    float gg = g4[2] + __uint_as_float(gxu[1] & 0xFFFF0000u) + bg;
    float go = g4[3] + __uint_as_float(gxu[1] << 16)          + bo;
    float it = sigm(gi), ft = sigm(gf), ot = sigm(go);
    float gt = tanh_f(gg);
    float cnew = ft * creg + it * gt;
    float hnew = ot * tanh_f(cnew);
    const bool act = (t < len);
    if (act) { creg = cnew; hreg = hnew; }
    {
      u32x2 pv = {packbf(hreg * PKEEP), (u32)(t + 1)};
      dev_st_u32x2(hbuf + (par ^ 1) * PLANE_U32 + m * REGION_U32 + row_l * 512 + ghc_w * 2, pv);
    }

    // ---- Gx prefetch for t+1 + out store
    if (t + 1 < T_STEPS)
      gxu = *(const u32x2*)(Gxb + ((long)((t + 1) * BATCH + gb)) * 512 + ghc_w * 2);
    out[(long)t * (BATCH * HID) + gb * HID + ghc_w] = act ? hnew : 0.0f;

    asm volatile("s_waitcnt vmcnt(0)" ::: "memory");
    __builtin_amdgcn_sched_barrier(0);
  }

  out[(long)T_STEPS * (BATCH * HID) + gb * HID + ghc_w] = hreg;
  out[(long)T_STEPS * (BATCH * HID) + BATCH * HID + gb * HID + ghc_w] = creg;
}

// ---------- v8 fallback (proven), verbatim ----------
template <int MODE>
__device__ __forceinline__ void recur_body8(
    const float* __restrict__ x, const int* __restrict__ lens,
    const float* __restrict__ W, const float* __restrict__ U,
    const float* __restrict__ bih, const float* __restrict__ bhh,
    float* __restrict__ out, u32* __restrict__ hbuf, const u32* __restrict__ xpk) {
  const int wg = blockIdx.x, tid = threadIdx.x;
  const int m = wg >> 4, n = wg & 15;
  const int lane = tid & 63, wave = tid >> 6;
  const int n16 = lane & 15, kgrp = lane >> 4;

  const int ghc_w = n * 16 + wave * 4 + (n16 & 3);
  const int grow = (n16 >> 2) * HID + ghc_w;
  s16x8 BUh[8], BUl[8], BWh[8], BWl[8];
#pragma unroll
  for (int ks = 0; ks < 8; ++ks) {
    const int base = grow * DIM + ks * 32 + kgrp * 8;
#pragma unroll
    for (int e = 0; e < 8; ++e) {
      float uv = U[base + e];
      u16 uh = f2bf_rne(uv);
      BUh[ks][e] = (short)uh;
      BUl[ks][e] = (short)f2bf_rne(uv - bf2f(uh));
      float wv = W[base + e];
      u16 wh = f2bf_rne(wv);
      BWh[ks][e] = (short)wh;
      BWl[ks][e] = (short)f2bf_rne(wv - bf2f(wh));
    }
  }

  const bool b2 = (lane >> 2) & 1, b3 = (lane >> 3) & 1;
  const int row_l = kgrp * 4 + (n16 >> 2);
  const int gb = m * RPG + row_l;
  const float bi  = bih[0 * HID + ghc_w] + bhh[0 * HID + ghc_w];
  const float bfo = bih[1 * HID + ghc_w] + bhh[1 * HID + ghc_w];
  const float bg  = bih[2 * HID + ghc_w] + bhh[2 * HID + ghc_w];
  const float bo  = bih[3 * HID + ghc_w] + bhh[3 * HID + ghc_w];
  const int len = lens[gb];
  float hreg = 0.0f, creg = 0.0f;

  const int rh = tid >> 7, p = tid & 127;

  __shared__ u32 hstage[2][RPG * HID];
  __shared__ u32 xstage[2][RPG * HID];

  {
    const int R = wave * 4;
    const long tb = (long)(m * RPG) * DIM;
#pragma unroll
    for (int r = 0; r < 4; ++r) {
      const long src = tb + (long)(R + r) * DIM + 4 * (lane ^ ((R + r) & 15));
      if constexpr (MODE == 0) gload_lds16(xpk + src, &xstage[0][(R + r) * HID]);
      else                     gload_lds16((const u32*)x + src, &xstage[0][(R + r) * HID]);
    }
  }

  for (int t = 0; t < T_STEPS; ++t) {
    const int par = t & 1;
    u32x4 P[8];
    {
      const u32* rb = hbuf + par * PLANE_U32 + m * REGION_U32 + rh * (8 * 512) + p * 4;
      for (;;) {
#pragma unroll
        for (int j = 0; j < 8; ++j)
          asm volatile("global_load_dwordx4 %0, %1, off sc0 sc1"
                       : "=v"(P[j]) : "v"(rb + j * 512) : "memory");
        asm volatile("s_waitcnt vmcnt(0)" ::: "memory");
        if (t == 0) break;
        bool stale = false;
#pragma unroll
        for (int j = 0; j < 8; ++j)
          stale |= (P[j][1] != (u32)t) || (P[j][3] != (u32)t);
        if (!__any(stale)) break;
      }
    }
    __builtin_amdgcn_sched_barrier(0);

#pragma unroll
    for (int j = 0; j < 8; ++j) {
      const int row = rh * 8 + j;
      const int byte = (row * 1024 + p * 8) ^ (row << 4);
      u32x2 v = {P[j][0], P[j][2]};
      *(u32x2*)((char*)hstage[par] + byte) = v;
    }
    __syncthreads();

    const int swz = n16 << 4;
    f32x4 ah = {0.f, 0.f, 0.f, 0.f}, ax = {0.f, 0.f, 0.f, 0.f};
#pragma unroll
    for (int ks = 0; ks < 8; ++ks) {
      const int bb = n16 * 1024 + (kgrp * 8 + ks * 32) * 4;
      u32x4 h0 = *(const u32x4*)((const char*)hstage[par] + (bb ^ swz));
      u32x4 h1 = *(const u32x4*)((const char*)hstage[par] + ((bb + 16) ^ swz));
      s16x8 Hh, Hl, Xh, Xl;
      unpack8(h0, h1, Hh, Hl);
      if constexpr (MODE == 0) {
        u32x4 x0 = *(const u32x4*)((const char*)xstage[par] + (bb ^ swz));
        u32x4 x1 = *(const u32x4*)((const char*)xstage[par] + ((bb + 16) ^ swz));
        unpack8(x0, x1, Xh, Xl);
      } else {
        f32x4 f0 = *(const f32x4*)((const char*)xstage[par] + (bb ^ swz));
        f32x4 f1 = *(const f32x4*)((const char*)xstage[par] + ((bb + 16) ^ swz));
#pragma unroll
        for (int e = 0; e < 8; ++e) {
          float v = (e < 4 ? f0[e] : f1[e - 4]) * PKEEP;
          unsigned hb = __float_as_uint(v) & 0xFFFF0000u;
          Xh[e] = (short)(hb >> 16);
          Xl[e] = (short)(u16)(__float_as_uint(v - __uint_as_float(hb)) >> 16);
        }
      }
      ah = __builtin_amdgcn_mfma_f32_16x16x32_bf16(Hh, BUh[ks], ah, 0, 0, 0);
      ax = __builtin_amdgcn_mfma_f32_16x16x32_bf16(Xh, BWh[ks], ax, 0, 0, 0);
      ah = __builtin_amdgcn_mfma_f32_16x16x32_bf16(Hl, BUh[ks], ah, 0, 0, 0);
      ax = __builtin_amdgcn_mfma_f32_16x16x32_bf16(Xl, BWh[ks], ax, 0, 0, 0);
      ah = __builtin_amdgcn_mfma_f32_16x16x32_bf16(Hh, BUl[ks], ah, 0, 0, 0);
      ax = __builtin_amdgcn_mfma_f32_16x16x32_bf16(Xh, BWl[ks], ax, 0, 0, 0);
    }

    f32x4 g4 = ah + ax;
    xpose4(g4, b2, b3);

    float gi = g4[0] + bi, gf = g4[1] + bfo, gg = g4[2] + bg, go = g4[3] + bo;
    float it = sigm(gi), ft = sigm(gf), ot = sigm(go);
    float gt = tanh_f(gg);
    float cnew = ft * creg + it * gt;
    float hnew = ot * tanh_f(cnew);
    const bool act = (t < len);
    if (act) { creg = cnew; hreg = hnew; }
    {
      u32x2 pv = {packbf(hreg * PKEEP), (u32)(t + 1)};
      dev_st_u32x2(hbuf + (par ^ 1) * PLANE_U32 + m * REGION_U32 + row_l * 512 + ghc_w * 2, pv);
    }

    if (t + 1 < T_STEPS) {
      const int R = wave * 4;
      const long tb = (long)(t + 1) * (BATCH * DIM) + (long)(m * RPG) * DIM;
#pragma unroll
      for (int r = 0; r < 4; ++r) {
        const long src = tb + (long)(R + r) * DIM + 4 * (lane ^ ((R + r) & 15));
        if constexpr (MODE == 0) gload_lds16(xpk + src, &xstage[par ^ 1][(R + r) * HID]);
        else                     gload_lds16((const u32*)x + src, &xstage[par ^ 1][(R + r) * HID]);
      }
    }
    out[(long)t * (BATCH * HID) + gb * HID + ghc_w] = act ? hnew : 0.0f;

    asm volatile("s_waitcnt vmcnt(0)" ::: "memory");
    __builtin_amdgcn_sched_barrier(0);
  }

  out[(long)T_STEPS * (BATCH * HID) + gb * HID + ghc_w] = hreg;
  out[(long)T_STEPS * (BATCH * HID) + BATCH * HID + gb * HID + ghc_w] = creg;
}

#define RECUR_PARAMS                                                          \
  const float* __restrict__ x, const int* __restrict__ lens,                  \
  const float* __restrict__ W, const float* __restrict__ U,                   \
  const float* __restrict__ bih, const float* __restrict__ bhh,               \
  float* __restrict__ out, u32* __restrict__ hbuf, const u32* __restrict__ xpk
#define RECUR_ARGS x, lens, W, U, bih, bhh, out, hbuf, xpk

__global__ __launch_bounds__(256, 1) void lstm_recur_v8_xpk(RECUR_PARAMS) { recur_body8<0>(RECUR_ARGS); }
__global__ __launch_bounds__(256, 1) void lstm_recur_v8_dir(RECUR_PARAMS) { recur_body8<1>(RECUR_ARGS); }

extern "C" void kernel_launch(void* const* d_in, const int* in_sizes, int n_in,
                              void* d_out, int out_size, void* d_ws, size_t ws_size,
                              hipStream_t stream) {
  const float* x   = (const float*)d_in[0];
  const int*   len = (const int*)d_in[1];
  const float* W   = (const float*)d_in[2];
  const float* U   = (const float*)d_in[3];
  const float* bih = (const float*)d_in[4];
  const float* bhh = (const float*)d_in[5];
  float* out = (float*)d_out;
  char*  ws  = (char*)d_ws;
  u32* hbuf = (u32*)(ws + HBUF_OFF);
  char* big = ws + BIG_OFF;

  lstm_zero_ws<<<dim3((ZERO_INTS + 255) / 256), dim3(256), 0, stream>>>(hbuf);

  const size_t need_gx = (size_t)BIG_OFF + (size_t)T_STEPS * BATCH * 512 * 4;  // ~257MB
  const size_t need_xp = (size_t)BIG_OFF + (size_t)XEL * 4;                    // ~129MB
  if (ws_size >= need_gx) {
    u32* Gxb = (u32*)big;
    lstm_gxp14<<<dim3(64 * (T_STEPS / TCHUNK)), dim3(256), 0, stream>>>(x, W, Gxb);
    lstm_recur_v14<<<dim3(64), dim3(256), 0, stream>>>(x, len, W, U, bih, bhh, out, hbuf, Gxb);
  } else if (ws_size >= need_xp) {
    u32* xpk = (u32*)big;
    lstm_xpack<<<dim3(32768), dim3(256), 0, stream>>>(x, xpk);
    lstm_recur_v8_xpk<<<dim3(64), dim3(256), 0, stream>>>(x, len, W, U, bih, bhh, out, hbuf, xpk);
  } else {
    lstm_recur_v8_dir<<<dim3(64), dim3(256), 0, stream>>>(x, len, W, U, bih, bhh, out, hbuf, nullptr);
  }
}